// Round 2
// baseline (3660.962 us; speedup 1.0000x reference)
//
#include <hip/hip_runtime.h>
#include <stdint.h>
#include <math.h>

// Problem constants (fixed by the reference)
#define T_TOK 8192      // B*S tokens
#define H_DIM 2048
#define I_DIM 1024
#define E_NUM 16
#define K_TOP 8
#define R_RANK 602
#define RP 640          // rank padded to 5*128 (zero-padded weights)
#define NPAIR 65536     // T_TOK * K_TOP (exact)
#define NPAIR_PAD (NPAIR + 128)
#define MAX_TILES 528   // sum ceil(Ne/128) <= 65536/128 + 16

typedef __attribute__((ext_vector_type(8))) short short8;
typedef __attribute__((ext_vector_type(4))) short short4v;
typedef __attribute__((ext_vector_type(4))) float f32x4;

__device__ __forceinline__ float bf2f(unsigned short s) {
  union { unsigned int i; float f; } u; u.i = ((unsigned int)s) << 16; return u.f;
}
__device__ __forceinline__ unsigned short f2bf(float f) {
  union { float f; unsigned int i; } u; u.f = f;
  unsigned int r = u.i + 0x7FFFu + ((u.i >> 16) & 1u);   // RNE, inputs finite
  return (unsigned short)(r >> 16);
}

// int-metadata buffer layout (in units of int)
#define IB_CNT  0
#define IB_OFFS 16
#define IB_CURS 33
#define IB_NT   49
#define IB_TE   50
#define IB_TP   (50 + MAX_TILES)
#define IB_TOTAL (50 + 2 * MAX_TILES)

// ---------------- router: fp32 logits, top-8, normalized weights ----------------
__global__ __launch_bounds__(64) void k_router(
    const float* __restrict__ x, const float* __restrict__ wr,
    float* __restrict__ logits, int* __restrict__ sel8, float* __restrict__ w8,
    int* __restrict__ cnt)
{
  int t = blockIdx.x;
  int lane = threadIdx.x;
  const float* xt = x + (long)t * H_DIM;
  float acc[E_NUM];
#pragma unroll
  for (int e = 0; e < E_NUM; ++e) acc[e] = 0.f;
  for (int h = lane * 4; h < H_DIM; h += 64 * 4) {
    float4 xv = *(const float4*)(xt + h);
#pragma unroll
    for (int e = 0; e < E_NUM; ++e) {
      float4 wv = *(const float4*)(wr + e * H_DIM + h);
      acc[e] += xv.x * wv.x + xv.y * wv.y + xv.z * wv.z + xv.w * wv.w;
    }
  }
#pragma unroll
  for (int e = 0; e < E_NUM; ++e) {
    float v = acc[e];
#pragma unroll
    for (int s = 32; s > 0; s >>= 1) v += __shfl_xor(v, s);
    acc[e] = v;
  }
  if (lane == 0) {
    float l[E_NUM]; float m = -3.4e38f;
#pragma unroll
    for (int e = 0; e < E_NUM; ++e) {
      l[e] = acc[e];
      logits[(long)t * E_NUM + e] = l[e];
      if (l[e] > m) m = l[e];
    }
    bool used[E_NUM];
#pragma unroll
    for (int e = 0; e < E_NUM; ++e) used[e] = false;
    int sel[K_TOP]; float ex[K_TOP]; float s = 0.f;
    for (int k = 0; k < K_TOP; ++k) {
      int best = 0; float bv = -3.4e38f;
      for (int e = 0; e < E_NUM; ++e)
        if (!used[e] && l[e] > bv) { bv = l[e]; best = e; }   // strict > = low-index tiebreak like lax.top_k
      used[best] = true; sel[k] = best;
      float ee = expf(bv - m); ex[k] = ee; s += ee;
    }
    float inv = 1.f / s;
    for (int k = 0; k < K_TOP; ++k) {
      sel8[t * K_TOP + k] = sel[k];
      w8[t * K_TOP + k] = ex[k] * inv;   // == topk-softmax renorm
      atomicAdd(&cnt[sel[k]], 1);
    }
  }
}

// ---------------- scan + tile table (trivial sizes; single thread) ----------------
__global__ void k_scan(int* ib) {
  if (threadIdx.x != 0 || blockIdx.x != 0) return;
  int o = 0, nt = 0;
  for (int e = 0; e < E_NUM; ++e) {
    ib[IB_OFFS + e] = o;
    ib[IB_CURS + e] = o;
    int c = ib[IB_CNT + e];
    for (int p = 0; p < c; p += 128) { ib[IB_TE + nt] = e; ib[IB_TP + nt] = o + p; ++nt; }
    o += c;
  }
  ib[IB_OFFS + E_NUM] = o;
  ib[IB_NT] = nt;
}

__global__ void k_build(const int* __restrict__ sel8, const float* __restrict__ w8,
                        int* ib, int* __restrict__ ptok, float* __restrict__ pw,
                        int* __restrict__ pidx)
{
  int t = blockIdx.x * 256 + threadIdx.x;
  if (t >= T_TOK) return;
  for (int k = 0; k < K_TOP; ++k) {
    int e = sel8[t * K_TOP + k];
    int pos = atomicAdd(&ib[IB_CURS + e], 1);
    ptok[pos] = t; pw[pos] = w8[t * K_TOP + k]; pidx[t * K_TOP + k] = pos;
  }
}

// ---------------- fp32 -> bf16 casts ----------------
__global__ void k_cast_plain(const float* __restrict__ src, unsigned short* __restrict__ dst, long n4) {
  long i = (long)blockIdx.x * 256 + threadIdx.x;
  if (i >= n4) return;
  long i4 = i * 4;
  float4 v = *(const float4*)(src + i4);
  short4v o; o.x = (short)f2bf(v.x); o.y = (short)f2bf(v.y); o.z = (short)f2bf(v.z); o.w = (short)f2bf(v.w);
  *(short4v*)(dst + i4) = o;
}

// row-padded: src [E][RS][C] -> dst [E][RD][C], rows >= RS zeroed (C % 4 == 0)
__global__ void k_cast_padrow(const float* __restrict__ src, unsigned short* __restrict__ dst,
                              int RS, int RD, int C, long n4) {
  long i = (long)blockIdx.x * 256 + threadIdx.x;
  if (i >= n4) return;
  long i4 = i * 4;
  long rowc = (long)RD * C;
  long e = i4 / rowc;
  long rem = i4 - e * rowc;
  int r = (int)(rem / C);
  int c = (int)(rem - (long)r * C);
  short4v o;
  if (r < RS) {
    float4 v = *(const float4*)(src + ((long)e * RS + r) * C + c);
    o.x = (short)f2bf(v.x); o.y = (short)f2bf(v.y); o.z = (short)f2bf(v.z); o.w = (short)f2bf(v.w);
  } else { o.x = 0; o.y = 0; o.z = 0; o.w = 0; }
  *(short4v*)(dst + i4) = o;
}

// col-padded: src [R][CS] -> dst [R][CD], cols >= CS zeroed (CS=602 odd -> scalar)
__global__ void k_cast_padcol(const float* __restrict__ src, unsigned short* __restrict__ dst,
                              int CS, int CD, long n) {
  long i = (long)blockIdx.x * 256 + threadIdx.x;
  if (i >= n) return;
  long row = i / CD;
  int c = (int)(i - row * CD);
  dst[i] = (c < CS) ? f2bf(src[row * CS + c]) : (unsigned short)0;
}

// ---------------- shared GEMM mainloop: 128x128 tile, BK=64, 16x16x32 bf16 MFMA ----------------
// NT layout everywhere: A [M,K] row-major, B [N,K] row-major.
// Staging: plain short8 loads -> LDS stores (m93-class; async gload re-added once baseline passes).
template <bool GATHER>
__device__ __forceinline__ void gemm_tile_loop(
    const unsigned short* __restrict__ A, int lda,
    const unsigned short* __restrict__ B, int ldb,
    int arow0, int segend, const int* __restrict__ ptok,
    int n0, int K,
    unsigned short* As, unsigned short* Bs,
    f32x4 (&acc)[4][4])
{
  const int tid = threadIdx.x;
  const int srow = tid >> 3;            // staging row (+ i*32)
  const int scolb = (tid & 7) * 16;     // staging byte col within 128B row
  const char* ap[4]; const char* bp[4];
#pragma unroll
  for (int i = 0; i < 4; ++i) {
    int rr = srow + i * 32;
    int arow;
    if (GATHER) {
      int p = arow0 + rr;
      if (p > segend - 1) p = segend - 1;  // clamp; masked at store
      arow = ptok[p];
    } else {
      arow = arow0 + rr;                   // pair buffers have 128 rows of slack
    }
    ap[i] = (const char*)A + (long)arow * lda * 2 + scolb;
    bp[i] = (const char*)B + (long)(n0 + rr) * ldb * 2 + scolb;
  }
  const int lane = tid & 63;
  const int wave = tid >> 6;
  const int wm = (wave >> 1) * 64, wn = (wave & 1) * 64;
  const int m16 = lane & 15, kg = lane >> 4;

  for (int kt = 0; kt < K; kt += 64) {
#pragma unroll
    for (int i = 0; i < 4; ++i) {
      short8 va = *(const short8*)ap[i];
      short8 vb = *(const short8*)bp[i];
      *(short8*)(As + (i * 256 + tid) * 8) = va;
      *(short8*)(Bs + (i * 256 + tid) * 8) = vb;
      ap[i] += 128; bp[i] += 128;
    }
    __syncthreads();
#pragma unroll
    for (int kk = 0; kk < 2; ++kk) {
      short8 af[4], bfr[4];
#pragma unroll
      for (int i = 0; i < 4; ++i)
        af[i] = *(const short8*)(As + (wm + i * 16 + m16) * 64 + kk * 32 + kg * 8);
#pragma unroll
      for (int j = 0; j < 4; ++j)
        bfr[j] = *(const short8*)(Bs + (wn + j * 16 + m16) * 64 + kk * 32 + kg * 8);
#pragma unroll
      for (int i = 0; i < 4; ++i)
#pragma unroll
        for (int j = 0; j < 4; ++j)
          acc[i][j] = __builtin_amdgcn_mfma_f32_16x16x32_bf16(af[i], bfr[j], acc[i][j], 0, 0, 0);
    }
    __syncthreads();   // protect LDS before next stage
  }
}

// ---------------- dense NT GEMM (full M), z selects (B,out) pair ----------------
template <int OUTF32>
__global__ __launch_bounds__(256, 2) void k_gemm_dense(
    const unsigned short* __restrict__ A,
    const unsigned short* __restrict__ B0, const unsigned short* __restrict__ B1,
    void* out0, void* out1, int K, int ldc)
{
  __shared__ __attribute__((aligned(16))) unsigned short As[128 * 64];
  __shared__ __attribute__((aligned(16))) unsigned short Bs[128 * 64];
  const unsigned short* B = blockIdx.z ? B1 : B0;
  void* outp = blockIdx.z ? out1 : out0;
  int m0 = blockIdx.x * 128, n0 = blockIdx.y * 128;
  f32x4 acc[4][4];
  f32x4 z = {0.f, 0.f, 0.f, 0.f};
#pragma unroll
  for (int i = 0; i < 4; ++i)
#pragma unroll
    for (int j = 0; j < 4; ++j) acc[i][j] = z;
  gemm_tile_loop<false>(A, K, B, K, m0, 0, nullptr, n0, K, As, Bs, acc);

  int tid = threadIdx.x, lane = tid & 63, wave = tid >> 6;
  int wm = (wave >> 1) * 64, wn = (wave & 1) * 64, m16 = lane & 15, kg = lane >> 4;
#pragma unroll
  for (int i = 0; i < 4; ++i)
#pragma unroll
    for (int r = 0; r < 4; ++r) {
      int row = m0 + wm + i * 16 + kg * 4 + r;
#pragma unroll
      for (int j = 0; j < 4; ++j) {
        int col = n0 + wn + j * 16 + m16;
        if (OUTF32) ((float*)outp)[(long)row * ldc + col] = acc[i][j][r];
        else ((unsigned short*)outp)[(long)row * ldc + col] = f2bf(acc[i][j][r]);
      }
    }
}

// ---------------- grouped (per-expert pair-segment) NT GEMM ----------------
// MODE 0: T = gather(xb) @ Aexp^T            -> outT bf16 [pair, RP]
// MODE 1: HW = silu(T @ Bg^T + base_g[tok])  -> HW bf16 [pair, I]
// MODE 2: HW = pw * HW * (T @ Bu^T + base_u[tok])   (in-place)
// MODE 3: T = HW @ Ad^T                      -> outT bf16 [pair, RP]
// MODE 4: out[tok] += T @ Bd^T               (fp32 atomicAdd epilogue)
template <int MODE>
__global__ __launch_bounds__(256, 2) void k_gemm_pairs(
    const int* __restrict__ ib,
    const int* __restrict__ ptok, const float* __restrict__ pw,
    const unsigned short* __restrict__ A, int lda,
    const unsigned short* __restrict__ Bbase, long bstrideE, int ldb,
    unsigned short* __restrict__ outT, int ldo,
    const unsigned short* __restrict__ baseGU,
    unsigned short* __restrict__ HW,
    float* __restrict__ outF,
    int K)
{
  int nt = ib[IB_NT];
  int bx = blockIdx.x;
  if (bx >= nt) return;
  int e = ib[IB_TE + bx];
  int p0 = ib[IB_TP + bx];
  int segend = ib[IB_OFFS + e + 1];
  int n0 = blockIdx.y * 128;
  const unsigned short* B = Bbase + (long)e * bstrideE;

  __shared__ __attribute__((aligned(16))) unsigned short As[128 * 64];
  __shared__ __attribute__((aligned(16))) unsigned short Bs[128 * 64];
  f32x4 acc[4][4];
  f32x4 zz = {0.f, 0.f, 0.f, 0.f};
#pragma unroll
  for (int i = 0; i < 4; ++i)
#pragma unroll
    for (int j = 0; j < 4; ++j) acc[i][j] = zz;

  gemm_tile_loop<(MODE == 0)>(A, lda, B, ldb, p0, segend, ptok, n0, K, As, Bs, acc);

  int tid = threadIdx.x, lane = tid & 63, wave = tid >> 6;
  int wm = (wave >> 1) * 64, wn = (wave & 1) * 64, m16 = lane & 15, kg = lane >> 4;
#pragma unroll
  for (int i = 0; i < 4; ++i)
#pragma unroll
    for (int r = 0; r < 4; ++r) {
      int prow = p0 + wm + i * 16 + kg * 4 + r;
      if (prow >= segend) continue;
      if (MODE == 0 || MODE == 3) {
        unsigned short* orow = outT + (long)prow * ldo + n0 + wn + m16;
#pragma unroll
        for (int j = 0; j < 4; ++j) orow[j * 16] = f2bf(acc[i][j][r]);
      } else if (MODE == 1) {
        int tok = ptok[prow];
        const unsigned short* brow = baseGU + (long)tok * I_DIM + n0 + wn + m16;
        unsigned short* hrow = HW + (long)prow * I_DIM + n0 + wn + m16;
#pragma unroll
        for (int j = 0; j < 4; ++j) {
          float g = acc[i][j][r] + bf2f(brow[j * 16]);
          float sg = g / (1.f + expf(-g));          // silu
          hrow[j * 16] = f2bf(sg);
        }
      } else if (MODE == 2) {
        int tok = ptok[prow];
        float w = pw[prow];
        const unsigned short* brow = baseGU + (long)tok * I_DIM + n0 + wn + m16;
        unsigned short* hrow = HW + (long)prow * I_DIM + n0 + wn + m16;
#pragma unroll
        for (int j = 0; j < 4; ++j) {
          float u = acc[i][j][r] + bf2f(brow[j * 16]);
          float hv = w * bf2f(hrow[j * 16]) * u;    // combine weight folded in
          hrow[j * 16] = f2bf(hv);
        }
      } else {  // MODE 4
        int tok = ptok[prow];
        float* orow = outF + (long)tok * H_DIM + n0 + wn + m16;
#pragma unroll
        for (int j = 0; j < 4; ++j) atomicAdd(&orow[j * 16], acc[i][j][r]);
      }
    }
}

// ---------------- hbar[t] = sum_k HW[pair(t,k)] ----------------
__global__ void k_combine(const unsigned short* __restrict__ HW, const int* __restrict__ pidx,
                          unsigned short* __restrict__ hbar)
{
  long idx = (long)blockIdx.x * 256 + threadIdx.x;
  if (idx >= (long)T_TOK * (I_DIM / 8)) return;
  int t = (int)(idx >> 7);
  int c = ((int)idx & 127) << 3;
  const int* pi = pidx + t * 8;
  float s[8];
#pragma unroll
  for (int j = 0; j < 8; ++j) s[j] = 0.f;
  for (int k = 0; k < 8; ++k) {
    short8 v = *(const short8*)(HW + (long)pi[k] * I_DIM + c);
#pragma unroll
    for (int j = 0; j < 8; ++j) s[j] += bf2f((unsigned short)v[j]);
  }
  short8 o;
#pragma unroll
  for (int j = 0; j < 8; ++j) o[j] = (short)f2bf(s[j]);
  *(short8*)(hbar + (long)t * I_DIM + c) = o;
}

// ---------------- launch ----------------
extern "C" void kernel_launch(void* const* d_in, const int* in_sizes, int n_in,
                              void* d_out, int out_size, void* d_ws, size_t ws_size,
                              hipStream_t stream) {
  const float* x  = (const float*)d_in[0];
  const float* wr = (const float*)d_in[1];
  const float* Wg = (const float*)d_in[2];
  const float* Wu = (const float*)d_in[3];
  const float* Wd = (const float*)d_in[4];
  const float* Ag = (const float*)d_in[5];
  const float* Bg = (const float*)d_in[6];
  const float* Au = (const float*)d_in[7];
  const float* Bu = (const float*)d_in[8];
  const float* Ad = (const float*)d_in[9];
  const float* Bd = (const float*)d_in[10];
  float* out = (float*)d_out;
  float* logits = out + (long)T_TOK * H_DIM;

  // ---- workspace layout (~350 MB, regions reused sequentially) ----
  char* p = (char*)d_ws;
  auto alloc = [&](size_t bytes) { char* r = p; p += (bytes + 255) & ~(size_t)255; return r; };
  unsigned short* xb    = (unsigned short*)alloc((size_t)T_TOK * H_DIM * 2);          // 33.6 MB
  unsigned short* WBA   = (unsigned short*)alloc((size_t)E_NUM * RP * H_DIM * 2);     // 41.9 MB (Wg+Wu / Ag / Au / Ad / Bd)
  unsigned short* WBB   = (unsigned short*)alloc((size_t)E_NUM * I_DIM * RP * 2);     // 21.0 MB (Bg / Bu / Wd)
  unsigned short* baseg = (unsigned short*)alloc((size_t)T_TOK * I_DIM * 2);          // 16.8 MB (later: hbar)
  unsigned short* baseu = (unsigned short*)alloc((size_t)T_TOK * I_DIM * 2);          // 16.8 MB
  unsigned short* Tbuf  = (unsigned short*)alloc((size_t)NPAIR_PAD * RP * 2);         // 84.0 MB
  unsigned short* HWb   = (unsigned short*)alloc((size_t)NPAIR_PAD * I_DIM * 2);      // 134.5 MB
  int*   ibuf  = (int*)alloc(IB_TOTAL * 4);
  int*   sel8  = (int*)alloc((size_t)T_TOK * K_TOP * 4);
  float* w8    = (float*)alloc((size_t)T_TOK * K_TOP * 4);
  int*   ptok  = (int*)alloc((size_t)NPAIR * 4);
  float* pwv   = (float*)alloc((size_t)NPAIR * 4);
  int*   pidx  = (int*)alloc((size_t)T_TOK * K_TOP * 4);
  unsigned short* hbar = baseg;   // overlay: baseg dead before hbar written
  (void)ws_size; (void)n_in; (void)in_sizes; (void)out_size;

  hipMemsetAsync(ibuf, 0, 16 * 4, stream);  // expert counts

  // x -> bf16; routing (fp32-exact)
  k_cast_plain<<<16384, 256, 0, stream>>>(x, xb, (long)T_TOK * H_DIM / 4);
  k_router<<<T_TOK, 64, 0, stream>>>(x, wr, logits, sel8, w8, ibuf + IB_CNT);
  k_scan<<<1, 1, 0, stream>>>(ibuf);
  k_build<<<T_TOK / 256, 256, 0, stream>>>(sel8, w8, ibuf, ptok, pwv, pidx);

  // base_g / base_u = xb @ {Wg,Wu}^T   (Wg,Wu staged in WBA)
  unsigned short* Wgb = WBA;
  unsigned short* Wub = WBA + (size_t)I_DIM * H_DIM;
  k_cast_plain<<<2048, 256, 0, stream>>>(Wg, Wgb, (long)I_DIM * H_DIM / 4);
  k_cast_plain<<<2048, 256, 0, stream>>>(Wu, Wub, (long)I_DIM * H_DIM / 4);
  k_gemm_dense<0><<<dim3(T_TOK / 128, I_DIM / 128, 2), 256, 0, stream>>>(
      xb, Wgb, Wub, baseg, baseu, H_DIM, I_DIM);

  // g path: T = gather(xb) @ Ag_e^T ; HW = silu(T @ Bg_e^T + base_g)
  k_cast_padrow<<<20480, 256, 0, stream>>>(Ag, WBA, R_RANK, RP, H_DIM, (long)E_NUM * RP * H_DIM / 4);
  k_gemm_pairs<0><<<dim3(MAX_TILES, RP / 128), 256, 0, stream>>>(
      ibuf, ptok, pwv, xb, H_DIM, WBA, (long)RP * H_DIM, H_DIM,
      Tbuf, RP, nullptr, nullptr, nullptr, H_DIM);
  k_cast_padcol<<<40960, 256, 0, stream>>>(Bg, WBB, R_RANK, RP, (long)E_NUM * I_DIM * RP);
  k_gemm_pairs<1><<<dim3(MAX_TILES, I_DIM / 128), 256, 0, stream>>>(
      ibuf, ptok, pwv, Tbuf, RP, WBB, (long)I_DIM * RP, RP,
      nullptr, I_DIM, baseg, HWb, nullptr, RP);

  // u path (reuses Tbuf): T = gather(xb) @ Au_e^T ; HW = pw * HW * (T @ Bu_e^T + base_u)
  k_cast_padrow<<<20480, 256, 0, stream>>>(Au, WBA, R_RANK, RP, H_DIM, (long)E_NUM * RP * H_DIM / 4);
  k_gemm_pairs<0><<<dim3(MAX_TILES, RP / 128), 256, 0, stream>>>(
      ibuf, ptok, pwv, xb, H_DIM, WBA, (long)RP * H_DIM, H_DIM,
      Tbuf, RP, nullptr, nullptr, nullptr, H_DIM);
  k_cast_padcol<<<40960, 256, 0, stream>>>(Bu, WBB, R_RANK, RP, (long)E_NUM * I_DIM * RP);
  k_gemm_pairs<2><<<dim3(MAX_TILES, I_DIM / 128), 256, 0, stream>>>(
      ibuf, ptok, pwv, Tbuf, RP, WBB, (long)I_DIM * RP, RP,
      nullptr, I_DIM, baseu, HWb, nullptr, RP);

  // hbar = per-token sum of weighted h   (overlaid on baseg, which is now dead)
  k_combine<<<(T_TOK * (I_DIM / 8)) / 256, 256, 0, stream>>>(HWb, pidx, hbar);

  // down LoRA stage 1: T = HW @ Ad_e^T
  k_cast_padrow<<<10240, 256, 0, stream>>>(Ad, WBA, R_RANK, RP, I_DIM, (long)E_NUM * RP * I_DIM / 4);
  k_gemm_pairs<3><<<dim3(MAX_TILES, RP / 128), 256, 0, stream>>>(
      ibuf, ptok, pwv, HWb, I_DIM, WBA, (long)RP * I_DIM, I_DIM,
      Tbuf, RP, nullptr, nullptr, nullptr, I_DIM);

  // out = hbar @ Wd^T  (fp32 store, full coverage; Wd staged in WBB)
  k_cast_plain<<<2048, 256, 0, stream>>>(Wd, WBB, (long)H_DIM * I_DIM / 4);
  k_gemm_dense<1><<<dim3(T_TOK / 128, H_DIM / 128, 1), 256, 0, stream>>>(
      hbar, WBB, WBB, out, out, I_DIM, H_DIM);

  // out += T @ Bd_e^T  (atomic scatter into token rows; Bd staged in WBA)
  k_cast_padcol<<<81920, 256, 0, stream>>>(Bd, WBA, R_RANK, RP, (long)E_NUM * H_DIM * RP);
  k_gemm_pairs<4><<<dim3(MAX_TILES, H_DIM / 128), 256, 0, stream>>>(
      ibuf, ptok, pwv, Tbuf, RP, WBA, (long)H_DIM * RP, RP,
      nullptr, H_DIM, nullptr, nullptr, out, RP);
}

// Round 3
// 2201.196 us; speedup vs baseline: 1.6632x; 1.6632x over previous
//
#include <hip/hip_runtime.h>
#include <stdint.h>
#include <math.h>

// Problem constants (fixed by the reference)
#define T_TOK 8192      // B*S tokens
#define H_DIM 2048
#define I_DIM 1024
#define E_NUM 16
#define K_TOP 8
#define R_RANK 602
#define RP 640          // rank padded to 5*128 (zero-padded weights)
#define NPAIR 65536     // T_TOK * K_TOP (exact)
#define NPAIR_PAD (NPAIR + 128)
#define MAX_TILES 528   // sum ceil(Ne/128) <= 65536/128 + 16

typedef __attribute__((ext_vector_type(8))) short short8;
typedef __attribute__((ext_vector_type(4))) short short4v;
typedef __attribute__((ext_vector_type(4))) float f32x4;

__device__ __forceinline__ float bf2f(unsigned short s) {
  union { unsigned int i; float f; } u; u.i = ((unsigned int)s) << 16; return u.f;
}
__device__ __forceinline__ unsigned short f2bf(float f) {
  union { float f; unsigned int i; } u; u.f = f;
  unsigned int r = u.i + 0x7FFFu + ((u.i >> 16) & 1u);   // RNE, inputs finite
  return (unsigned short)(r >> 16);
}

typedef __attribute__((address_space(1))) const unsigned int glob_u32;
typedef __attribute__((address_space(3))) unsigned int lds_u32;

__device__ __forceinline__ void gload16(const void* g, void* l) {
  // async global->LDS, 16B per lane; LDS dest must be wave-uniform base + lane*16
  __builtin_amdgcn_global_load_lds((glob_u32*)g, (lds_u32*)l, 16, 0, 0);
}

// int-metadata buffer layout (in units of int)
#define IB_CNT  0
#define IB_OFFS 16
#define IB_CURS 33
#define IB_NT   49
#define IB_TE   50
#define IB_TP   (50 + MAX_TILES)
#define IB_TOTAL (50 + 2 * MAX_TILES)

// ---------------- logits + top-8 (no atomics; 4 waves/block, wave per token) ----------------
__global__ __launch_bounds__(256) void k_logits(
    const float* __restrict__ x, const float* __restrict__ wr,
    float* __restrict__ logits, int* __restrict__ sel8, float* __restrict__ w8)
{
  int tid = threadIdx.x;
  int t = blockIdx.x * 4 + (tid >> 6);
  int lane = tid & 63;
  const float* xt = x + (long)t * H_DIM;
  float acc[E_NUM];
#pragma unroll
  for (int e = 0; e < E_NUM; ++e) acc[e] = 0.f;
  for (int h = lane * 4; h < H_DIM; h += 64 * 4) {
    float4 xv = *(const float4*)(xt + h);
#pragma unroll
    for (int e = 0; e < E_NUM; ++e) {
      float4 wv = *(const float4*)(wr + e * H_DIM + h);
      acc[e] += xv.x * wv.x + xv.y * wv.y + xv.z * wv.z + xv.w * wv.w;
    }
  }
#pragma unroll
  for (int e = 0; e < E_NUM; ++e) {
    float v = acc[e];
#pragma unroll
    for (int s = 32; s > 0; s >>= 1) v += __shfl_xor(v, s);
    acc[e] = v;
  }
  if (lane == 0) {
    float l[E_NUM]; float m = -3.4e38f;
#pragma unroll
    for (int e = 0; e < E_NUM; ++e) {
      l[e] = acc[e];
      logits[(long)t * E_NUM + e] = l[e];
      if (l[e] > m) m = l[e];
    }
    bool used[E_NUM];
#pragma unroll
    for (int e = 0; e < E_NUM; ++e) used[e] = false;
    int sel[K_TOP]; float ex[K_TOP]; float s = 0.f;
    for (int k = 0; k < K_TOP; ++k) {
      int best = 0; float bv = -3.4e38f;
      for (int e = 0; e < E_NUM; ++e)
        if (!used[e] && l[e] > bv) { bv = l[e]; best = e; }   // strict > = low-index tiebreak like lax.top_k
      used[best] = true; sel[k] = best;
      float ee = expf(bv - m); ex[k] = ee; s += ee;
    }
    float inv = 1.f / s;
    for (int k = 0; k < K_TOP; ++k) {
      sel8[t * K_TOP + k] = sel[k];
      w8[t * K_TOP + k] = ex[k] * inv;   // == topk-softmax renorm
    }
  }
}

// ---------------- per-block LDS histogram -> 16 global atomics per block ----------------
__global__ __launch_bounds__(256) void k_hist(const int* __restrict__ sel8, int* __restrict__ cnt) {
  __shared__ int lh[E_NUM];
  int tid = threadIdx.x;
  if (tid < E_NUM) lh[tid] = 0;
  __syncthreads();
  int t = blockIdx.x * 256 + tid;
#pragma unroll
  for (int k = 0; k < K_TOP; ++k) atomicAdd(&lh[sel8[t * K_TOP + k]], 1);
  __syncthreads();
  if (tid < E_NUM) atomicAdd(&cnt[tid], lh[tid]);
}

// ---------------- scan + tile table (trivial sizes; single thread) ----------------
__global__ void k_scan(int* ib) {
  if (threadIdx.x != 0 || blockIdx.x != 0) return;
  int o = 0, nt = 0;
  for (int e = 0; e < E_NUM; ++e) {
    ib[IB_OFFS + e] = o;
    ib[IB_CURS + e] = o;
    int c = ib[IB_CNT + e];
    for (int p = 0; p < c; p += 128) { ib[IB_TE + nt] = e; ib[IB_TP + nt] = o + p; ++nt; }
    o += c;
  }
  ib[IB_OFFS + E_NUM] = o;
  ib[IB_NT] = nt;
}

// ---------------- pair-list build: block reserves per-expert ranges (16 atomics/block) ----------------
__global__ __launch_bounds__(256) void k_build(
    const int* __restrict__ sel8, const float* __restrict__ w8,
    int* ib, int* __restrict__ ptok, float* __restrict__ pw,
    int* __restrict__ pidx)
{
  __shared__ int lh[E_NUM], lbase[E_NUM];
  int tid = threadIdx.x;
  if (tid < E_NUM) lh[tid] = 0;
  __syncthreads();
  int t = blockIdx.x * 256 + tid;
  int e8[K_TOP], r8[K_TOP];
#pragma unroll
  for (int k = 0; k < K_TOP; ++k) {
    int e = sel8[t * K_TOP + k];
    e8[k] = e;
    r8[k] = atomicAdd(&lh[e], 1);        // LDS atomic: local rank within block
  }
  __syncthreads();
  if (tid < E_NUM) lbase[tid] = atomicAdd(&ib[IB_CURS + tid], lh[tid]);
  __syncthreads();
#pragma unroll
  for (int k = 0; k < K_TOP; ++k) {
    int pos = lbase[e8[k]] + r8[k];
    ptok[pos] = t; pw[pos] = w8[t * K_TOP + k]; pidx[t * K_TOP + k] = pos;
  }
}

// ---------------- fp32 -> bf16 casts ----------------
__global__ void k_cast_plain(const float* __restrict__ src, unsigned short* __restrict__ dst, long n4) {
  long i = (long)blockIdx.x * 256 + threadIdx.x;
  if (i >= n4) return;
  long i4 = i * 4;
  float4 v = *(const float4*)(src + i4);
  short4v o; o.x = (short)f2bf(v.x); o.y = (short)f2bf(v.y); o.z = (short)f2bf(v.z); o.w = (short)f2bf(v.w);
  *(short4v*)(dst + i4) = o;
}

// row-padded: src [E][RS][C] -> dst [E][RD][C], rows >= RS zeroed (C % 4 == 0)
__global__ void k_cast_padrow(const float* __restrict__ src, unsigned short* __restrict__ dst,
                              int RS, int RD, int C, long n4) {
  long i = (long)blockIdx.x * 256 + threadIdx.x;
  if (i >= n4) return;
  long i4 = i * 4;
  long rowc = (long)RD * C;
  long e = i4 / rowc;
  long rem = i4 - e * rowc;
  int r = (int)(rem / C);
  int c = (int)(rem - (long)r * C);
  short4v o;
  if (r < RS) {
    float4 v = *(const float4*)(src + ((long)e * RS + r) * C + c);
    o.x = (short)f2bf(v.x); o.y = (short)f2bf(v.y); o.z = (short)f2bf(v.z); o.w = (short)f2bf(v.w);
  } else { o.x = 0; o.y = 0; o.z = 0; o.w = 0; }
  *(short4v*)(dst + i4) = o;
}

// col-padded, vectorized: src [R][CS] -> dst [R][CD], cols >= CS zeroed. CD % 8 == 0.
__global__ void k_cast_padcol(const float* __restrict__ src, unsigned short* __restrict__ dst,
                              int CS, int CD, long n8) {
  long i = (long)blockIdx.x * 256 + threadIdx.x;
  if (i >= n8) return;
  int cpr = CD >> 3;                 // chunks per row
  long row = i / cpr;
  int c0 = (int)(i - row * cpr) << 3;
  const float* srow = src + row * CS;
  short8 o;
#pragma unroll
  for (int j = 0; j < 8; ++j) {
    int c = c0 + j;
    o[j] = (c < CS) ? (short)f2bf(srow[c]) : (short)0;
  }
  *(short8*)(dst + row * CD + c0) = o;
}

// ---------------- shared GEMM mainloop: 128x128 tile, BK=64, 16x16x32 bf16 MFMA ----------------
// NT layout everywhere: A [M,K] row-major, B [N,K] row-major.
// Staging: async global_load_lds width=16 (m97-style).
template <bool GATHER>
__device__ __forceinline__ void gemm_tile_loop(
    const unsigned short* __restrict__ A, int lda,
    const unsigned short* __restrict__ B, int ldb,
    int arow0, int segend, const int* __restrict__ ptok,
    int n0, int K,
    unsigned short* As, unsigned short* Bs,
    f32x4 (&acc)[4][4])
{
  const int tid = threadIdx.x;
  const int srow = tid >> 3;            // staging row (+ i*32)
  const int scolb = (tid & 7) * 16;     // staging byte col within 128B row
  const char* ap[4]; const char* bp[4];
#pragma unroll
  for (int i = 0; i < 4; ++i) {
    int rr = srow + i * 32;
    int arow;
    if (GATHER) {
      int p = arow0 + rr;
      if (p > segend - 1) p = segend - 1;  // clamp; masked at store
      arow = ptok[p];
    } else {
      arow = arow0 + rr;                   // pair buffers have 128 rows of slack
    }
    ap[i] = (const char*)A + (long)arow * lda * 2 + scolb;
    bp[i] = (const char*)B + (long)(n0 + rr) * ldb * 2 + scolb;
  }
  const int lane = tid & 63;
  const int wave = tid >> 6;
  const int wm = (wave >> 1) * 64, wn = (wave & 1) * 64;
  const int m16 = lane & 15, kg = lane >> 4;

  for (int kt = 0; kt < K; kt += 64) {
#pragma unroll
    for (int i = 0; i < 4; ++i) {
      gload16(ap[i], As + (i * 256 + tid) * 8);
      gload16(bp[i], Bs + (i * 256 + tid) * 8);
      ap[i] += 128; bp[i] += 128;
    }
    __syncthreads();   // drains vmcnt (async LDS DMA) before LDS reads
#pragma unroll
    for (int kk = 0; kk < 2; ++kk) {
      short8 af[4], bfr[4];
#pragma unroll
      for (int i = 0; i < 4; ++i)
        af[i] = *(const short8*)(As + (wm + i * 16 + m16) * 64 + kk * 32 + kg * 8);
#pragma unroll
      for (int j = 0; j < 4; ++j)
        bfr[j] = *(const short8*)(Bs + (wn + j * 16 + m16) * 64 + kk * 32 + kg * 8);
#pragma unroll
      for (int i = 0; i < 4; ++i)
#pragma unroll
        for (int j = 0; j < 4; ++j)
          acc[i][j] = __builtin_amdgcn_mfma_f32_16x16x32_bf16(af[i], bfr[j], acc[i][j], 0, 0, 0);
    }
    __syncthreads();   // protect LDS before next stage
  }
}

// ---------------- dense NT GEMM (full M), z selects (B,out) pair ----------------
template <int OUTF32>
__global__ __launch_bounds__(256, 2) void k_gemm_dense(
    const unsigned short* __restrict__ A,
    const unsigned short* __restrict__ B0, const unsigned short* __restrict__ B1,
    void* out0, void* out1, int K, int ldc)
{
  __shared__ __attribute__((aligned(16))) unsigned short As[128 * 64];
  __shared__ __attribute__((aligned(16))) unsigned short Bs[128 * 64];
  const unsigned short* B = blockIdx.z ? B1 : B0;
  void* outp = blockIdx.z ? out1 : out0;
  int m0 = blockIdx.x * 128, n0 = blockIdx.y * 128;
  f32x4 acc[4][4];
  f32x4 z = {0.f, 0.f, 0.f, 0.f};
#pragma unroll
  for (int i = 0; i < 4; ++i)
#pragma unroll
    for (int j = 0; j < 4; ++j) acc[i][j] = z;
  gemm_tile_loop<false>(A, K, B, K, m0, 0, nullptr, n0, K, As, Bs, acc);

  int tid = threadIdx.x, lane = tid & 63, wave = tid >> 6;
  int wm = (wave >> 1) * 64, wn = (wave & 1) * 64, m16 = lane & 15, kg = lane >> 4;
#pragma unroll
  for (int i = 0; i < 4; ++i)
#pragma unroll
    for (int r = 0; r < 4; ++r) {
      int row = m0 + wm + i * 16 + kg * 4 + r;
#pragma unroll
      for (int j = 0; j < 4; ++j) {
        int col = n0 + wn + j * 16 + m16;
        if (OUTF32) ((float*)outp)[(long)row * ldc + col] = acc[i][j][r];
        else ((unsigned short*)outp)[(long)row * ldc + col] = f2bf(acc[i][j][r]);
      }
    }
}

// ---------------- grouped (per-expert pair-segment) NT GEMM ----------------
// MODE 0: T = gather(xb) @ Aexp^T            -> outT bf16 [pair, RP]
// MODE 1: HW = silu(T @ Bg^T + base_g[tok])  -> HW bf16 [pair, I]
// MODE 2: HW = pw * HW * (T @ Bu^T + base_u[tok])   (in-place)
// MODE 3: T = HW @ Ad^T                      -> outT bf16 [pair, RP]
// MODE 4: out[tok] += T @ Bd^T               (fp32 atomicAdd epilogue)
template <int MODE>
__global__ __launch_bounds__(256, 2) void k_gemm_pairs(
    const int* __restrict__ ib,
    const int* __restrict__ ptok, const float* __restrict__ pw,
    const unsigned short* __restrict__ A, int lda,
    const unsigned short* __restrict__ Bbase, long bstrideE, int ldb,
    unsigned short* __restrict__ outT, int ldo,
    const unsigned short* __restrict__ baseGU,
    unsigned short* __restrict__ HW,
    float* __restrict__ outF,
    int K)
{
  int nt = ib[IB_NT];
  int bx = blockIdx.x;
  if (bx >= nt) return;
  int e = ib[IB_TE + bx];
  int p0 = ib[IB_TP + bx];
  int segend = ib[IB_OFFS + e + 1];
  int n0 = blockIdx.y * 128;
  const unsigned short* B = Bbase + (long)e * bstrideE;

  __shared__ __attribute__((aligned(16))) unsigned short As[128 * 64];
  __shared__ __attribute__((aligned(16))) unsigned short Bs[128 * 64];
  f32x4 acc[4][4];
  f32x4 zz = {0.f, 0.f, 0.f, 0.f};
#pragma unroll
  for (int i = 0; i < 4; ++i)
#pragma unroll
    for (int j = 0; j < 4; ++j) acc[i][j] = zz;

  gemm_tile_loop<(MODE == 0)>(A, lda, B, ldb, p0, segend, ptok, n0, K, As, Bs, acc);

  int tid = threadIdx.x, lane = tid & 63, wave = tid >> 6;
  int wm = (wave >> 1) * 64, wn = (wave & 1) * 64, m16 = lane & 15, kg = lane >> 4;
#pragma unroll
  for (int i = 0; i < 4; ++i)
#pragma unroll
    for (int r = 0; r < 4; ++r) {
      int prow = p0 + wm + i * 16 + kg * 4 + r;
      if (prow >= segend) continue;
      if (MODE == 0 || MODE == 3) {
        unsigned short* orow = outT + (long)prow * ldo + n0 + wn + m16;
#pragma unroll
        for (int j = 0; j < 4; ++j) orow[j * 16] = f2bf(acc[i][j][r]);
      } else if (MODE == 1) {
        int tok = ptok[prow];
        const unsigned short* brow = baseGU + (long)tok * I_DIM + n0 + wn + m16;
        unsigned short* hrow = HW + (long)prow * I_DIM + n0 + wn + m16;
#pragma unroll
        for (int j = 0; j < 4; ++j) {
          float g = acc[i][j][r] + bf2f(brow[j * 16]);
          float sg = g / (1.f + expf(-g));          // silu
          hrow[j * 16] = f2bf(sg);
        }
      } else if (MODE == 2) {
        int tok = ptok[prow];
        float w = pw[prow];
        const unsigned short* brow = baseGU + (long)tok * I_DIM + n0 + wn + m16;
        unsigned short* hrow = HW + (long)prow * I_DIM + n0 + wn + m16;
#pragma unroll
        for (int j = 0; j < 4; ++j) {
          float u = acc[i][j][r] + bf2f(brow[j * 16]);
          float hv = w * bf2f(hrow[j * 16]) * u;    // combine weight folded in
          hrow[j * 16] = f2bf(hv);
        }
      } else {  // MODE 4
        int tok = ptok[prow];
        float* orow = outF + (long)tok * H_DIM + n0 + wn + m16;
#pragma unroll
        for (int j = 0; j < 4; ++j) atomicAdd(&orow[j * 16], acc[i][j][r]);
      }
    }
}

// ---------------- hbar[t] = sum_k HW[pair(t,k)] ----------------
__global__ void k_combine(const unsigned short* __restrict__ HW, const int* __restrict__ pidx,
                          unsigned short* __restrict__ hbar)
{
  long idx = (long)blockIdx.x * 256 + threadIdx.x;
  if (idx >= (long)T_TOK * (I_DIM / 8)) return;
  int t = (int)(idx >> 7);
  int c = ((int)idx & 127) << 3;
  const int* pi = pidx + t * 8;
  float s[8];
#pragma unroll
  for (int j = 0; j < 8; ++j) s[j] = 0.f;
  for (int k = 0; k < 8; ++k) {
    short8 v = *(const short8*)(HW + (long)pi[k] * I_DIM + c);
#pragma unroll
    for (int j = 0; j < 8; ++j) s[j] += bf2f((unsigned short)v[j]);
  }
  short8 o;
#pragma unroll
  for (int j = 0; j < 8; ++j) o[j] = (short)f2bf(s[j]);
  *(short8*)(hbar + (long)t * I_DIM + c) = o;
}

// ---------------- launch ----------------
extern "C" void kernel_launch(void* const* d_in, const int* in_sizes, int n_in,
                              void* d_out, int out_size, void* d_ws, size_t ws_size,
                              hipStream_t stream) {
  const float* x  = (const float*)d_in[0];
  const float* wr = (const float*)d_in[1];
  const float* Wg = (const float*)d_in[2];
  const float* Wu = (const float*)d_in[3];
  const float* Wd = (const float*)d_in[4];
  const float* Ag = (const float*)d_in[5];
  const float* Bg = (const float*)d_in[6];
  const float* Au = (const float*)d_in[7];
  const float* Bu = (const float*)d_in[8];
  const float* Ad = (const float*)d_in[9];
  const float* Bd = (const float*)d_in[10];
  float* out = (float*)d_out;
  float* logits = out + (long)T_TOK * H_DIM;

  // ---- workspace layout (~350 MB, regions reused sequentially) ----
  char* p = (char*)d_ws;
  auto alloc = [&](size_t bytes) { char* r = p; p += (bytes + 255) & ~(size_t)255; return r; };
  unsigned short* xb    = (unsigned short*)alloc((size_t)T_TOK * H_DIM * 2);          // 33.6 MB
  unsigned short* WBA   = (unsigned short*)alloc((size_t)E_NUM * RP * H_DIM * 2);     // 41.9 MB (Wg+Wu / Ag / Au / Ad / Bd)
  unsigned short* WBB   = (unsigned short*)alloc((size_t)E_NUM * I_DIM * RP * 2);     // 21.0 MB (Bg / Bu / Wd)
  unsigned short* baseg = (unsigned short*)alloc((size_t)T_TOK * I_DIM * 2);          // 16.8 MB (later: hbar)
  unsigned short* baseu = (unsigned short*)alloc((size_t)T_TOK * I_DIM * 2);          // 16.8 MB
  unsigned short* Tbuf  = (unsigned short*)alloc((size_t)NPAIR_PAD * RP * 2);         // 84.0 MB
  unsigned short* HWb   = (unsigned short*)alloc((size_t)NPAIR_PAD * I_DIM * 2);      // 134.5 MB
  int*   ibuf  = (int*)alloc(IB_TOTAL * 4);
  int*   sel8  = (int*)alloc((size_t)T_TOK * K_TOP * 4);
  float* w8    = (float*)alloc((size_t)T_TOK * K_TOP * 4);
  int*   ptok  = (int*)alloc((size_t)NPAIR * 4);
  float* pwv   = (float*)alloc((size_t)NPAIR * 4);
  int*   pidx  = (int*)alloc((size_t)T_TOK * K_TOP * 4);
  unsigned short* hbar = baseg;   // overlay: baseg dead before hbar written
  (void)ws_size; (void)n_in; (void)in_sizes; (void)out_size;

  hipMemsetAsync(ibuf, 0, 16 * 4, stream);  // expert counts

  // x -> bf16; routing (fp32-exact, contention-free)
  k_cast_plain<<<16384, 256, 0, stream>>>(x, xb, (long)T_TOK * H_DIM / 4);
  k_logits<<<T_TOK / 4, 256, 0, stream>>>(x, wr, logits, sel8, w8);
  k_hist<<<T_TOK / 256, 256, 0, stream>>>(sel8, ibuf + IB_CNT);
  k_scan<<<1, 1, 0, stream>>>(ibuf);
  k_build<<<T_TOK / 256, 256, 0, stream>>>(sel8, w8, ibuf, ptok, pwv, pidx);

  // base_g / base_u = xb @ {Wg,Wu}^T   (Wg,Wu staged in WBA)
  unsigned short* Wgb = WBA;
  unsigned short* Wub = WBA + (size_t)I_DIM * H_DIM;
  k_cast_plain<<<2048, 256, 0, stream>>>(Wg, Wgb, (long)I_DIM * H_DIM / 4);
  k_cast_plain<<<2048, 256, 0, stream>>>(Wu, Wub, (long)I_DIM * H_DIM / 4);
  k_gemm_dense<0><<<dim3(T_TOK / 128, I_DIM / 128, 2), 256, 0, stream>>>(
      xb, Wgb, Wub, baseg, baseu, H_DIM, I_DIM);

  // g path: T = gather(xb) @ Ag_e^T ; HW = silu(T @ Bg_e^T + base_g)
  k_cast_padrow<<<20480, 256, 0, stream>>>(Ag, WBA, R_RANK, RP, H_DIM, (long)E_NUM * RP * H_DIM / 4);
  k_gemm_pairs<0><<<dim3(MAX_TILES, RP / 128), 256, 0, stream>>>(
      ibuf, ptok, pwv, xb, H_DIM, WBA, (long)RP * H_DIM, H_DIM,
      Tbuf, RP, nullptr, nullptr, nullptr, H_DIM);
  k_cast_padcol<<<5120, 256, 0, stream>>>(Bg, WBB, R_RANK, RP, (long)E_NUM * I_DIM * RP / 8);
  k_gemm_pairs<1><<<dim3(MAX_TILES, I_DIM / 128), 256, 0, stream>>>(
      ibuf, ptok, pwv, Tbuf, RP, WBB, (long)I_DIM * RP, RP,
      nullptr, I_DIM, baseg, HWb, nullptr, RP);

  // u path (reuses Tbuf): T = gather(xb) @ Au_e^T ; HW = pw * HW * (T @ Bu_e^T + base_u)
  k_cast_padrow<<<20480, 256, 0, stream>>>(Au, WBA, R_RANK, RP, H_DIM, (long)E_NUM * RP * H_DIM / 4);
  k_gemm_pairs<0><<<dim3(MAX_TILES, RP / 128), 256, 0, stream>>>(
      ibuf, ptok, pwv, xb, H_DIM, WBA, (long)RP * H_DIM, H_DIM,
      Tbuf, RP, nullptr, nullptr, nullptr, H_DIM);
  k_cast_padcol<<<5120, 256, 0, stream>>>(Bu, WBB, R_RANK, RP, (long)E_NUM * I_DIM * RP / 8);
  k_gemm_pairs<2><<<dim3(MAX_TILES, I_DIM / 128), 256, 0, stream>>>(
      ibuf, ptok, pwv, Tbuf, RP, WBB, (long)I_DIM * RP, RP,
      nullptr, I_DIM, baseu, HWb, nullptr, RP);

  // hbar = per-token sum of weighted h   (overlaid on baseg, which is now dead)
  k_combine<<<(T_TOK * (I_DIM / 8)) / 256, 256, 0, stream>>>(HWb, pidx, hbar);

  // down LoRA stage 1: T = HW @ Ad_e^T
  k_cast_padrow<<<10240, 256, 0, stream>>>(Ad, WBA, R_RANK, RP, I_DIM, (long)E_NUM * RP * I_DIM / 4);
  k_gemm_pairs<3><<<dim3(MAX_TILES, RP / 128), 256, 0, stream>>>(
      ibuf, ptok, pwv, HWb, I_DIM, WBA, (long)RP * I_DIM, I_DIM,
      Tbuf, RP, nullptr, nullptr, nullptr, I_DIM);

  // out = hbar @ Wd^T  (fp32 store, full coverage; Wd staged in WBB)
  k_cast_plain<<<2048, 256, 0, stream>>>(Wd, WBB, (long)H_DIM * I_DIM / 4);
  k_gemm_dense<1><<<dim3(T_TOK / 128, H_DIM / 128, 1), 256, 0, stream>>>(
      hbar, WBB, WBB, out, out, I_DIM, H_DIM);

  // out += T @ Bd_e^T  (atomic scatter into token rows; Bd staged in WBA)
  k_cast_padcol<<<10240, 256, 0, stream>>>(Bd, WBA, R_RANK, RP, (long)E_NUM * H_DIM * RP / 8);
  k_gemm_pairs<4><<<dim3(MAX_TILES, H_DIM / 128), 256, 0, stream>>>(
      ibuf, ptok, pwv, Tbuf, RP, WBA, (long)H_DIM * RP, RP,
      nullptr, H_DIM, nullptr, nullptr, out, RP);
}